// Round 1
// baseline (1088.880 us; speedup 1.0000x reference)
//
#include <hip/hip_runtime.h>
#include <stdint.h>

#define NTAGS 512
#define STAG 510
#define PTAG 511
#define SEQ 512
#define L2E 1.4426950408889634f
#define LN2 0.6931471805599453f
#define SMEM_BYTES 148672

typedef int   v8i __attribute__((ext_vector_type(8)));
typedef float v4f __attribute__((ext_vector_type(4)));

// ---------------- setup: E = exp(trans) quantized to MX-fp4, swizzled ----------------
// E rows: n (next). 512 fp4/row = 256 B = 16 chunks of 16 B; chunk c stored at c^(n&7).
// es2: uint32[512][4]; dword g, byte kk = e8m0 scale of k-block (kk*4+g).
__global__ void crf_setup_k(const float* __restrict__ trans, uint8_t* __restrict__ ws)
{
    int t = blockIdx.x * blockDim.x + threadIdx.x;   // 8192 threads
    int n = t >> 4, blk = t & 15;
    const float* row = trans + n * NTAGS + blk * 32;
    float v[32]; float mx = -3.0e38f;
    #pragma unroll
    for (int k = 0; k < 32; ++k) { v[k] = row[k]; mx = fmaxf(mx, v[k]); }
    int e = (int)floorf(mx * L2E - 1.5849625f);      // max q in (3,6]
    int byt = e + 127; byt = byt < 0 ? 0 : (byt > 254 ? 254 : byt);
    float eeff = (float)(byt - 127);
    uint32_t out[4] = {0u,0u,0u,0u};
    #pragma unroll
    for (int k = 0; k < 32; ++k) {
        float q = exp2f(v[k] * L2E - eeff);
        uint32_t cc;
        if      (q < 0.25f) cc = 0u;
        else if (q < 0.75f) cc = 1u;   // 0.5
        else if (q < 1.25f) cc = 2u;   // 1
        else if (q < 1.75f) cc = 3u;   // 1.5
        else if (q < 2.5f)  cc = 4u;   // 2
        else if (q < 3.5f)  cc = 5u;   // 3
        else if (q < 5.0f)  cc = 6u;   // 4
        else                cc = 7u;   // 6
        out[k >> 3] |= cc << ((k & 7) * 4);          // low nibble = even k
    }
    uint32_t* E = (uint32_t*)ws;
    int chunk = blk ^ (n & 7);
    int base = n * 64 + chunk * 4;
    E[base] = out[0]; E[base+1] = out[1]; E[base+2] = out[2]; E[base+3] = out[3];
    ws[131072 + n*16 + (blk & 3)*4 + (blk >> 2)] = (uint8_t)byt;
}

// ---------------- main: 8 WGs x 16 batches, 512 threads (8 waves) ----------------
// LDS: Es fp4 131072 | es2 8192 | aq fp8 8192 | Mb 64 | mxb 1024 | dml2 64 | rr 64
__global__ __launch_bounds__(512, 2) void crf_main_k(
    const float* __restrict__ inp, const float* __restrict__ trans,
    const uint8_t* __restrict__ ws, float* __restrict__ part)
{
    extern __shared__ uint8_t sm[];
    uint32_t* Es   = (uint32_t*)sm;
    uint32_t* es2  = (uint32_t*)(sm + 131072);
    uint8_t*  aq   = sm + 139264;
    float*    Mb   = (float*)(sm + 147456);
    float*    mxb  = (float*)(sm + 147520);   // [16][16], stride 16
    float*    dml2 = (float*)(sm + 148544);
    float*    rr   = (float*)(sm + 148608);

    const int tid = threadIdx.x;
    const int w = tid >> 6, l = tid & 63, c = l & 15, g = l >> 4;
    const int wg = blockIdx.x;

    // copy E + es2 (139264 B = 8704 int4) from ws into LDS
    {
        const int4* src = (const int4*)ws;
        int4* dst = (int4*)sm;
        for (int i = tid; i < 8704; i += 512) dst[i] = src[i];
    }

    // ---- init: alpha_1[n] = inp[b,0,n] + trans[n,STAG]; quantize fp8 (scale 2^-7) ----
    int ib = tid >> 4, iblk = tid & 15;
    float v[32]; float bm = -3.0e38f;
    if (tid < 256) {
        const float* ein = inp + (wg*16 + ib) * SEQ * NTAGS + iblk * 32;
        #pragma unroll
        for (int k = 0; k < 32; ++k) {
            v[k] = ein[k] + trans[(iblk*32 + k)*NTAGS + STAG];
            bm = fmaxf(bm, v[k]);
        }
        mxb[ib*16 + iblk] = bm;
    }
    __syncthreads();
    if (tid < 16) {
        float m = -3.0e38f;
        #pragma unroll
        for (int k = 0; k < 16; ++k) m = fmaxf(m, mxb[tid*16 + k]);
        Mb[tid] = m;
    }
    __syncthreads();
    if (tid < 256) {
        float m = Mb[ib];
        uint32_t ob[8];
        #pragma unroll
        for (int kp = 0; kp < 16; ++kp) {
            float q0 = exp2f((v[2*kp]   - m) * L2E + 7.0f);
            float q1 = exp2f((v[2*kp+1] - m) * L2E + 7.0f);
            int pk = __builtin_amdgcn_cvt_pk_fp8_f32(q0, q1, 0, false);
            ((uint16_t*)ob)[kp] = (uint16_t)(pk & 0xffff);
        }
        int4* aq4w = (int4*)aq;
        int ch0 = (iblk*2)     ^ (ib & 7);
        int ch1 = (iblk*2 + 1) ^ (ib & 7);
        aq4w[ib*32 + ch0] = ((int4*)ob)[0];
        aq4w[ib*32 + ch1] = ((int4*)ob)[1];
    }
    __syncthreads();

    // ---- persistent B fragments (fp4 E): 16 x int4 in registers ----
    int4 Bf[16];
    #pragma unroll
    for (int i = 0; i < 4; ++i) {
        int n = (w*4 + i)*16 + c;
        #pragma unroll
        for (int kk = 0; kk < 4; ++kk) {
            int chunk = (kk*4 + g) ^ (n & 7);
            Bf[i*4 + kk] = ((const int4*)Es)[n*16 + chunk];
        }
    }
    uint32_t esc0 = es2[(((w*4+0)*16 + c))*4 + g];
    uint32_t esc1 = es2[(((w*4+1)*16 + c))*4 + g];
    uint32_t esc2 = es2[(((w*4+2)*16 + c))*4 + g];
    uint32_t esc3 = es2[(((w*4+3)*16 + c))*4 + g];

    int aoffA[8];
    #pragma unroll
    for (int kk = 0; kk < 4; ++kk) {
        aoffA[2*kk]   = c*32 + ((kk*8 + g*2)     ^ (c & 7));
        aoffA[2*kk+1] = c*32 + ((kk*8 + g*2 + 1) ^ (c & 7));
    }
    const float* ep0 = inp + (wg*16 + g*4 + 0) * SEQ * NTAGS + w*64 + c;
    const float* ep1 = inp + (wg*16 + g*4 + 1) * SEQ * NTAGS + w*64 + c;
    const float* ep2 = inp + (wg*16 + g*4 + 2) * SEQ * NTAGS + w*64 + c;
    const float* ep3 = inp + (wg*16 + g*4 + 3) * SEQ * NTAGS + w*64 + c;
    const int4* aq4 = (const int4*)aq;
    const int ASCALE = 120;   // e8m0 byte for 2^-7, byte0, opsel_a = 0

#define MFMA_ONE(KK, II, ESC) do { \
    const int4 bf_ = Bf[(II)*4 + (KK)]; \
    v8i B_; B_[0]=bf_.x; B_[1]=bf_.y; B_[2]=bf_.z; B_[3]=bf_.w; B_[4]=0; B_[5]=0; B_[6]=0; B_[7]=0; \
    D[II] = __builtin_amdgcn_mfma_scale_f32_16x16x128_f8f6f4(A_, B_, D[II], 0, 4, 0, ASCALE, KK, (int)(ESC)); \
} while (0)

#define MFMA_K(KK) do { \
    int4 a0_ = aq4[aoffA[2*(KK)]]; int4 a1_ = aq4[aoffA[2*(KK)+1]]; \
    v8i A_; A_[0]=a0_.x; A_[1]=a0_.y; A_[2]=a0_.z; A_[3]=a0_.w; A_[4]=a1_.x; A_[5]=a1_.y; A_[6]=a1_.z; A_[7]=a1_.w; \
    MFMA_ONE(KK, 0, esc0); MFMA_ONE(KK, 1, esc1); MFMA_ONE(KK, 2, esc2); MFMA_ONE(KK, 3, esc3); \
} while (0)

    for (int s = 1; s < SEQ; ++s) {
        // emission prefetch (used in phase B)
        float em[4][4];
        {
            int so = s * NTAGS;
            #pragma unroll
            for (int i = 0; i < 4; ++i) {
                em[0][i] = ep0[so + i*16];
                em[1][i] = ep1[so + i*16];
                em[2][i] = ep2[so + i*16];
                em[3][i] = ep3[so + i*16];
            }
        }
        // ---- MFMA: acc[b,n] = sum_p a[b,p] * E[n,p] ----
        v4f D[4];
        #pragma unroll
        for (int i = 0; i < 4; ++i) { D[i][0]=0.f; D[i][1]=0.f; D[i][2]=0.f; D[i][3]=0.f; }
        MFMA_K(0); MFMA_K(1); MFMA_K(2); MFMA_K(3);

        // ---- phase B: u0 = emit*log2e + ~log2(acc); per-batch max -> new offset ----
        float tt[4][4], u0[4][4];
        #pragma unroll
        for (int j = 0; j < 4; ++j) {
            #pragma unroll
            for (int i = 0; i < 4; ++i) {
                float acc = D[i][j];
                tt[j][i] = em[j][i] * L2E;
                int ex = (int)((__float_as_uint(acc) >> 23) & 255u) - 127;
                u0[j][i] = tt[j][i] + (float)ex;
            }
        }
        float rm[4];
        #pragma unroll
        for (int j = 0; j < 4; ++j)
            rm[j] = fmaxf(fmaxf(u0[j][0], u0[j][1]), fmaxf(u0[j][2], u0[j][3]));
        #pragma unroll
        for (int m = 1; m <= 8; m <<= 1) {
            #pragma unroll
            for (int j = 0; j < 4; ++j) rm[j] = fmaxf(rm[j], __shfl_xor(rm[j], m, 64));
        }
        if (c == 0) {
            #pragma unroll
            for (int j = 0; j < 4; ++j) mxb[(g*4 + j)*16 + w] = rm[j];
        }
        __syncthreads();
        if (tid < 16) {
            float u = -3.0e38f;
            #pragma unroll
            for (int k = 0; k < 8; ++k) u = fmaxf(u, mxb[tid*16 + k]);
            Mb[tid] += LN2 * u;
            dml2[tid] = -u;
        }
        __syncthreads();

        if (s < SEQ - 1) {
            // ---- quantize a' = acc * 2^(tt + dm), fixed fp8 scale 2^-7 ----
            #pragma unroll
            for (int j = 0; j < 4; ++j) {
                int b = g*4 + j;
                float dm7 = dml2[b] + 7.0f;
                #pragma unroll
                for (int p = 0; p < 2; ++p) {
                    float q0 = D[2*p][j]   * exp2f(tt[j][2*p]   + dm7);
                    float q1 = D[2*p+1][j] * exp2f(tt[j][2*p+1] + dm7);
                    int pk = __builtin_amdgcn_cvt_pk_fp8_f32(q0, q1, 0, false);
                    aq[b*512 + ((w*4 + 2*p)     ^ (b & 7))*16 + c] = (uint8_t)(pk & 255);
                    aq[b*512 + ((w*4 + 2*p + 1) ^ (b & 7))*16 + c] = (uint8_t)((pk >> 8) & 255);
                }
            }
            __syncthreads();
        } else {
            // ---- final: loss_b = Mb + max + ln(sum exp(rel - max)), rel = ln(acc)+emit+transStop ----
            float ts[4];
            #pragma unroll
            for (int i = 0; i < 4; ++i) ts[i] = trans[PTAG*NTAGS + w*64 + i*16 + c];
            float rel[4][4];
            #pragma unroll
            for (int j = 0; j < 4; ++j) {
                #pragma unroll
                for (int i = 0; i < 4; ++i)
                    rel[j][i] = LN2 * __log2f(D[i][j]) + em[j][i] + ts[i];
            }
            float r2[4];
            #pragma unroll
            for (int j = 0; j < 4; ++j)
                r2[j] = fmaxf(fmaxf(rel[j][0], rel[j][1]), fmaxf(rel[j][2], rel[j][3]));
            #pragma unroll
            for (int m = 1; m <= 8; m <<= 1) {
                #pragma unroll
                for (int j = 0; j < 4; ++j) r2[j] = fmaxf(r2[j], __shfl_xor(r2[j], m, 64));
            }
            if (c == 0) {
                #pragma unroll
                for (int j = 0; j < 4; ++j) mxb[(g*4 + j)*16 + w] = r2[j];
            }
            __syncthreads();
            if (tid < 16) {
                float u = -3.0e38f;
                #pragma unroll
                for (int k = 0; k < 8; ++k) u = fmaxf(u, mxb[tid*16 + k]);
                rr[tid] = u;
            }
            __syncthreads();
            #pragma unroll
            for (int j = 0; j < 4; ++j) {
                float R = rr[g*4 + j];
                float sj = exp2f((rel[j][0]-R)*L2E) + exp2f((rel[j][1]-R)*L2E)
                         + exp2f((rel[j][2]-R)*L2E) + exp2f((rel[j][3]-R)*L2E);
                #pragma unroll
                for (int m = 1; m <= 8; m <<= 1) sj += __shfl_xor(sj, m, 64);
                if (c == 0) mxb[(g*4 + j)*16 + w] = sj;
            }
            __syncthreads();
            if (tid < 16) {
                float S = 0.f;
                #pragma unroll
                for (int k = 0; k < 8; ++k) S += mxb[tid*16 + k];
                part[wg*16 + tid] = Mb[tid] + rr[tid] + LN2 * __log2f(S);
            }
        }
    }
#undef MFMA_K
#undef MFMA_ONE
}

__global__ void crf_final_k(const float* __restrict__ part, float* __restrict__ out)
{
    int t = threadIdx.x;  // 64
    float vsum = part[t] + part[t + 64];
    #pragma unroll
    for (int off = 32; off; off >>= 1) vsum += __shfl_down(vsum, off, 64);
    if (t == 0) out[0] = vsum;
}

extern "C" void kernel_launch(void* const* d_in, const int* in_sizes, int n_in,
                              void* d_out, int out_size, void* d_ws, size_t ws_size,
                              hipStream_t stream)
{
    (void)in_sizes; (void)n_in; (void)out_size; (void)ws_size;
    const float* inp   = (const float*)d_in[0];
    // d_in[1] = tags: unused by the reference computation (partition function only)
    const float* trans = (const float*)d_in[2];
    uint8_t* ws = (uint8_t*)d_ws;
    float* part = (float*)(ws + 139264);

    hipFuncSetAttribute(reinterpret_cast<const void*>(crf_main_k),
                        hipFuncAttributeMaxDynamicSharedMemorySize, SMEM_BYTES);

    crf_setup_k<<<64, 128, 0, stream>>>(trans, ws);
    crf_main_k<<<8, 512, SMEM_BYTES, stream>>>(inp, trans, ws, part);
    crf_final_k<<<1, 64, 0, stream>>>(part, (float*)d_out);
}

// Round 2
// 890.942 us; speedup vs baseline: 1.2222x; 1.2222x over previous
//
#include <hip/hip_runtime.h>
#include <stdint.h>

#define NTAGS 512
#define STAG 510
#define PTAG 511
#define SEQ 512
#define L2E 1.4426950408889634f
#define LN2 0.6931471805599453f
#define SMEM_BYTES 157376

typedef int   v8i __attribute__((ext_vector_type(8)));
typedef float v4f __attribute__((ext_vector_type(4)));

// max with a DPP-permuted copy (ctrl must be a literal)
#define DPPMAX(X, CTRL) fmaxf((X), __int_as_float(__builtin_amdgcn_update_dpp( \
    0, __float_as_int(X), (CTRL), 0xF, 0xF, false)))
// 0xB1 = quad_perm(1,0,3,2) = xor1 ; 0x4E = quad_perm(2,3,0,1) = xor2
// 0x141 = row_half_mirror   = xor7 ; 0x140 = row_mirror        = xor15

// ---------------- setup: E = exp(trans) -> MX-fp4, k-dim permuted ----------------
// Permutation pi: k-block KB (32 k's), idx in [0,32):
//   p = (KB>>1)*64 + (idx&3)*16 + (KB&1)*8 + (idx>>2)
// so that the producer's 4 bytes per (batch, i=0..3) are one contiguous u32.
__global__ void crf_setup_k(const float* __restrict__ trans, uint8_t* __restrict__ ws)
{
    int t = blockIdx.x * blockDim.x + threadIdx.x;   // 8192 threads
    int n = t >> 4, KB = t & 15;
    const float* row = trans + n * NTAGS;
    int wq = KB >> 1, h = KB & 1;
    float v[32]; float mx = -3.0e38f;
    #pragma unroll
    for (int k = 0; k < 32; ++k) {
        int p = wq*64 + (k & 3)*16 + h*8 + (k >> 2);
        v[k] = row[p]; mx = fmaxf(mx, v[k]);
    }
    int e = (int)floorf(mx * L2E - 1.5849625f);      // max q in (3,6]
    int byt = e + 127; byt = byt < 0 ? 0 : (byt > 254 ? 254 : byt);
    float eeff = (float)(byt - 127);
    uint32_t out[4] = {0u,0u,0u,0u};
    #pragma unroll
    for (int k = 0; k < 32; ++k) {
        float q = exp2f(v[k] * L2E - eeff);
        uint32_t cc;
        if      (q < 0.25f) cc = 0u;
        else if (q < 0.75f) cc = 1u;
        else if (q < 1.25f) cc = 2u;
        else if (q < 1.75f) cc = 3u;
        else if (q < 2.5f)  cc = 4u;
        else if (q < 3.5f)  cc = 5u;
        else if (q < 5.0f)  cc = 6u;
        else                cc = 7u;
        out[k >> 3] |= cc << ((k & 7) * 4);
    }
    uint32_t* E = (uint32_t*)ws;
    int chunk = KB ^ (n & 7);
    int base = n * 64 + chunk * 4;
    E[base] = out[0]; E[base+1] = out[1]; E[base+2] = out[2]; E[base+3] = out[3];
    ws[131072 + n*16 + (KB & 3)*4 + (KB >> 2)] = (uint8_t)byt;
}

// ---------------- main: 8 WGs x 16 batches, 512 threads (8 waves) ----------------
// LDS: Es 131072 | es2 8192 | aq[2] 16384 | scs[2] 512 | mxp[2] 128 | mxb 512 | ssum 512 | Gb 64
__global__ __launch_bounds__(512, 2) void crf_main_k(
    const float* __restrict__ inp, const float* __restrict__ trans,
    const uint8_t* __restrict__ ws, float* __restrict__ part)
{
    extern __shared__ uint8_t sm[];
    uint32_t* Es   = (uint32_t*)sm;
    uint32_t* es2  = (uint32_t*)(sm + 131072);
    uint8_t*  aqb  = sm + 139264;                 // 2 x 8192
    uint8_t*  scb  = sm + 155648;                 // 2 x 256
    int*      mxp  = (int*)(sm + 156160);         // 2 x 16
    float*    mxb  = (float*)(sm + 156288);       // [16][8]
    float*    ssum = (float*)(sm + 156800);       // [16][8]
    float*    Gb   = (float*)(sm + 157312);       // [16]

    const int tid = threadIdx.x;
    const int w = tid >> 6, l = tid & 63, c = l & 15, g = l >> 4;
    const int wg = blockIdx.x;
    const int b0 = g * 4;

    // copy E + es2 (139264 B = 8704 int4) into LDS
    {
        const int4* src = (const int4*)ws;
        int4* dst = (int4*)sm;
        for (int i = tid; i < 8704; i += 512) dst[i] = src[i];
    }

    const float* ep[4];
    #pragma unroll
    for (int j = 0; j < 4; ++j)
        ep[j] = inp + (size_t)(wg*16 + b0 + j) * (SEQ*NTAGS) + w*64 + c;

// quantize 4 values (i=0..3) of batch b0+J into AQ/SC with fold RJ.
// Block = (w, c>>3): reduce over i (local) and c-bits 0..2 (DPP).
#define QUANT_STORE(J, V0, V1, V2, V3, RJ, AQ, SC) do { \
    float bm_ = fmaxf(fmaxf(V0, V1), fmaxf(V2, V3)); \
    bm_ = DPPMAX(bm_, 0xB1); bm_ = DPPMAX(bm_, 0x4E); bm_ = DPPMAX(bm_, 0x141); \
    int be_ = (int)((__float_as_uint(bm_) >> 23) & 255u) - 127; \
    be_ = be_ < -60 ? -60 : be_; \
    float qs_ = __int_as_float((uint32_t)(133 - be_) << 23); \
    int t_ = __builtin_amdgcn_cvt_pk_fp8_f32((V0)*qs_, (V1)*qs_, 0, false); \
    t_ = __builtin_amdgcn_cvt_pk_fp8_f32((V2)*qs_, (V3)*qs_, t_, true); \
    int bb_ = b0 + (J); \
    ((uint32_t*)(AQ))[bb_*128 + (((w*4 + (c>>2)) ^ (bb_ & 7)) << 2) + (c & 3)] = (uint32_t)t_; \
    if ((c & 7) == 0) { \
        int B_ = w*2 + (c>>3); \
        int sb_ = 121 + be_ - (RJ); sb_ = sb_ < 0 ? 0 : (sb_ > 254 ? 254 : sb_); \
        (SC)[bb_*16 + ((B_ & 3)<<2) + (B_>>2)] = (uint8_t)sb_; \
    } \
    bmout_[J] = bm_; \
} while (0)

    // ---- init: alpha_1[n] = inp[b,0,n] + trans[n,STAG]; global max; MX-fp8 store ----
    float vv[4][4];
    {
        float tr[4];
        #pragma unroll
        for (int i = 0; i < 4; ++i) tr[i] = trans[(w*64 + i*16 + c)*NTAGS + STAG];
        #pragma unroll
        for (int j = 0; j < 4; ++j) {
            #pragma unroll
            for (int i = 0; i < 4; ++i)
                vv[j][i] = ep[j][i*16] + tr[i];
        }
    }
    float Mj[4];
    #pragma unroll
    for (int j = 0; j < 4; ++j) {
        float m = fmaxf(fmaxf(vv[j][0], vv[j][1]), fmaxf(vv[j][2], vv[j][3]));
        #pragma unroll
        for (int msk = 1; msk <= 8; msk <<= 1) m = fmaxf(m, __shfl_xor(m, msk, 64));
        if (c == 0) mxb[(b0 + j)*8 + w] = m;
    }
    __syncthreads();
    float G[4];
    #pragma unroll
    for (int j = 0; j < 4; ++j) {
        float m = -3.0e38f;
        #pragma unroll
        for (int k = 0; k < 8; ++k) m = fmaxf(m, mxb[(b0 + j)*8 + k]);
        Mj[j] = m;
        G[j] = m * L2E;
    }
    {
        float bmout_[4];
        uint8_t* AQ = aqb + 8192; uint8_t* SC = scb + 256;   // buffer 1
        #pragma unroll
        for (int j = 0; j < 4; ++j) {
            float q0 = exp2f((vv[j][0] - Mj[j]) * L2E);
            float q1 = exp2f((vv[j][1] - Mj[j]) * L2E);
            float q2 = exp2f((vv[j][2] - Mj[j]) * L2E);
            float q3 = exp2f((vv[j][3] - Mj[j]) * L2E);
            QUANT_STORE(j, q0, q1, q2, q3, 0, AQ, SC);
        }
        (void)bmout_;
    }
    if (w == 0 && c == 0) { int4 z; z.x=0; z.y=0; z.z=0; z.w=0; *(int4*)(mxp + 16 + g*4) = z; }
    __syncthreads();

    // ---- persistent B fragments (fp4 E) + E scales ----
    int4 Bf[16];
    #pragma unroll
    for (int i = 0; i < 4; ++i) {
        int n = (w*4 + i)*16 + c;
        #pragma unroll
        for (int kk = 0; kk < 4; ++kk)
            Bf[i*4 + kk] = ((const int4*)Es)[n*16 + ((kk*4 + g) ^ (n & 7))];
    }
    int esc[4];
    #pragma unroll
    for (int i = 0; i < 4; ++i) esc[i] = (int)es2[((w*4 + i)*16 + c)*4 + g];

    int aoffA[8];
    #pragma unroll
    for (int kk = 0; kk < 4; ++kk) {
        aoffA[2*kk]   = c*32 + ((kk*8 + g*2)     ^ (c & 7));
        aoffA[2*kk+1] = c*32 + ((kk*8 + g*2 + 1) ^ (c & 7));
    }
    const int scoff = c*16 + g*4;

#define MFMA_ONE(KK, II) do { \
    const int4 bf_ = Bf[(II)*4 + (KK)]; \
    v8i B_; B_[0]=bf_.x; B_[1]=bf_.y; B_[2]=bf_.z; B_[3]=bf_.w; B_[4]=0; B_[5]=0; B_[6]=0; B_[7]=0; \
    D[II] = __builtin_amdgcn_mfma_scale_f32_16x16x128_f8f6f4(A_, B_, D[II], 0, 4, KK, (int)scA, KK, esc[II]); \
} while (0)

#define MFMA_K(KK) do { \
    int4 a0_ = aq4[aoffA[2*(KK)]]; int4 a1_ = aq4[aoffA[2*(KK)+1]]; \
    v8i A_; A_[0]=a0_.x; A_[1]=a0_.y; A_[2]=a0_.z; A_[3]=a0_.w; A_[4]=a1_.x; A_[5]=a1_.y; A_[6]=a1_.z; A_[7]=a1_.w; \
    MFMA_ONE(KK, 0); MFMA_ONE(KK, 1); MFMA_ONE(KK, 2); MFMA_ONE(KK, 3); \
} while (0)

    for (int s = 1; s < SEQ; ++s) {
        const int cur = s & 1, nxt = cur ^ 1;

        // emission prefetch
        float em[4][4];
        {
            const int so = s * NTAGS;
            #pragma unroll
            for (int j = 0; j < 4; ++j) {
                #pragma unroll
                for (int i = 0; i < 4; ++i)
                    em[j][i] = ep[j][so + i*16];
            }
        }
        int4 Pv = *(const int4*)(mxp + cur*16 + g*4);
        uint32_t scA = *(const uint32_t*)(scb + cur*256 + scoff);
        const int4* aq4 = (const int4*)(aqb + cur*8192);

        v4f D[4];
        #pragma unroll
        for (int i = 0; i < 4; ++i) { D[i][0]=0.f; D[i][1]=0.f; D[i][2]=0.f; D[i][3]=0.f; }
        MFMA_K(0); MFMA_K(1); MFMA_K(2); MFMA_K(3);

        if (s < SEQ - 1) {
            int Rj[4];
            #pragma unroll
            for (int j = 0; j < 4; ++j) {
                Rj[j] = ((const int*)&Pv)[j] + 8;
                G[j] += (float)Rj[j];
            }
            float bmout_[4];
            uint8_t* AQ = aqb + nxt*8192; uint8_t* SC = scb + nxt*256;
            #pragma unroll
            for (int j = 0; j < 4; ++j) {
                float v0 = D[0][j] * exp2f(em[j][0] * L2E);
                float v1 = D[1][j] * exp2f(em[j][1] * L2E);
                float v2 = D[2][j] * exp2f(em[j][2] * L2E);
                float v3 = D[3][j] * exp2f(em[j][3] * L2E);
                QUANT_STORE(j, v0, v1, v2, v3, Rj[j], AQ, SC);
            }
            if (w == 0) {
                int4 post;
                #pragma unroll
                for (int j = 0; j < 4; ++j) {
                    float bb = DPPMAX(bmout_[j], 0x140);   // 16-lane (batch) max
                    int be0 = (int)((__float_as_uint(bb) >> 23) & 255u) - 127;
                    ((int*)&post)[j] = be0 - Rj[j];
                }
                if (c == 0) *(int4*)(mxp + nxt*16 + g*4) = post;
            }
            __syncthreads();
        } else {
            // ---- final: loss_b = LN2*(G + max_x + log2 sum 2^(x - max)) ----
            float ts[4];
            #pragma unroll
            for (int i = 0; i < 4; ++i) ts[i] = trans[PTAG*NTAGS + w*64 + i*16 + c];
            float x[4][4];
            #pragma unroll
            for (int j = 0; j < 4; ++j) {
                #pragma unroll
                for (int i = 0; i < 4; ++i)
                    x[j][i] = __log2f(D[i][j]) + (em[j][i] + ts[i]) * L2E;
            }
            #pragma unroll
            for (int j = 0; j < 4; ++j) {
                float m = fmaxf(fmaxf(x[j][0], x[j][1]), fmaxf(x[j][2], x[j][3]));
                #pragma unroll
                for (int msk = 1; msk <= 8; msk <<= 1) m = fmaxf(m, __shfl_xor(m, msk, 64));
                if (c == 0) mxb[(b0 + j)*8 + w] = m;
            }
            if (w == 0 && c == 0) {
                #pragma unroll
                for (int j = 0; j < 4; ++j) Gb[b0 + j] = G[j];
            }
            __syncthreads();
            #pragma unroll
            for (int j = 0; j < 4; ++j) {
                float XM = -3.0e38f;
                #pragma unroll
                for (int k = 0; k < 8; ++k) XM = fmaxf(XM, mxb[(b0 + j)*8 + k]);
                float sj = exp2f(x[j][0] - XM) + exp2f(x[j][1] - XM)
                         + exp2f(x[j][2] - XM) + exp2f(x[j][3] - XM);
                #pragma unroll
                for (int msk = 1; msk <= 8; msk <<= 1) sj += __shfl_xor(sj, msk, 64);
                if (c == 0) ssum[(b0 + j)*8 + w] = sj;
            }
            __syncthreads();
            if (tid < 16) {
                float S = 0.f, XM = -3.0e38f;
                #pragma unroll
                for (int k = 0; k < 8; ++k) { S += ssum[tid*8 + k]; XM = fmaxf(XM, mxb[tid*8 + k]); }
                part[wg*16 + tid] = LN2 * (Gb[tid] + XM + __log2f(S));
            }
        }
    }
#undef MFMA_K
#undef MFMA_ONE
#undef QUANT_STORE
}

__global__ void crf_final_k(const float* __restrict__ part, float* __restrict__ out)
{
    int t = threadIdx.x;  // 64
    float vsum = part[t] + part[t + 64];
    #pragma unroll
    for (int off = 32; off; off >>= 1) vsum += __shfl_down(vsum, off, 64);
    if (t == 0) out[0] = vsum;
}

extern "C" void kernel_launch(void* const* d_in, const int* in_sizes, int n_in,
                              void* d_out, int out_size, void* d_ws, size_t ws_size,
                              hipStream_t stream)
{
    (void)in_sizes; (void)n_in; (void)out_size; (void)ws_size;
    const float* inp   = (const float*)d_in[0];
    // d_in[1] = tags: unused (partition function only)
    const float* trans = (const float*)d_in[2];
    uint8_t* ws = (uint8_t*)d_ws;
    float* part = (float*)(ws + 139264);

    hipFuncSetAttribute(reinterpret_cast<const void*>(crf_main_k),
                        hipFuncAttributeMaxDynamicSharedMemorySize, SMEM_BYTES);

    crf_setup_k<<<64, 128, 0, stream>>>(trans, ws);
    crf_main_k<<<8, 512, SMEM_BYTES, stream>>>(inp, trans, ws, part);
    crf_final_k<<<1, 64, 0, stream>>>(part, (float*)d_out);
}